// Round 1
// baseline (27.794 us; speedup 1.0000x reference)
//
#include <hip/hip_runtime.h>

// PresetEmbedding: N=2048, L=256, H=64, NT=16, MAXC=32
// out[n][l][h] = (t>=8) ? cat_table[round(t*32 + cat_val)][h]
//                       : num_val * conv_w[t*64+h] + conv_b[t*64+h]
// where t = u_in[n][l][2] (exact integer in f32), cat_val = u_in[n][l][0],
// num_val = u_in[n][l][1].

#define N_ 2048
#define L_ 256
#define H_ 64

__global__ __launch_bounds__(256) void preset_embed_kernel(
    const float* __restrict__ u_in,      // N*L*3
    const float* __restrict__ conv_w,    // NT*H = 1024
    const float* __restrict__ conv_b,    // NT*H = 1024
    const float* __restrict__ cat_table, // MAXC*NT*H = 512*64
    float* __restrict__ out)             // N*L*H
{
    const int total_v4 = N_ * L_ * (H_ / 4);        // one float4 per thread-iter
    const int stride   = gridDim.x * blockDim.x;
    for (int i = blockIdx.x * blockDim.x + threadIdx.x; i < total_v4; i += stride) {
        const int pair  = i >> 4;        // n*L + l
        const int lane4 = i & 15;        // which float4 within H=64

        // broadcast 12-byte read of u_in[pair] across the 16-lane group
        const float* u = u_in + (size_t)pair * 3;
        const float cat_val = u[0];
        const float num_val = u[1];
        const float type_f  = u[2];
        const int   t       = __float2int_rn(type_f);

        float4 r;
        if (t >= 8) {
            // categorical: gather 16B from the 128 KiB (L2-resident) table
            const int idx = __float2int_rn(type_f * 32.0f + cat_val);
            r = reinterpret_cast<const float4*>(cat_table + (size_t)idx * H_)[lane4];
        } else {
            // numeric: affine with per-type weights (4 KiB, cache-resident)
            const float4 wv = reinterpret_cast<const float4*>(conv_w + t * H_)[lane4];
            const float4 bv = reinterpret_cast<const float4*>(conv_b + t * H_)[lane4];
            r.x = fmaf(num_val, wv.x, bv.x);
            r.y = fmaf(num_val, wv.y, bv.y);
            r.z = fmaf(num_val, wv.z, bv.z);
            r.w = fmaf(num_val, wv.w, bv.w);
        }
        reinterpret_cast<float4*>(out)[i] = r;   // coalesced: 1 KiB per wave
    }
}

extern "C" void kernel_launch(void* const* d_in, const int* in_sizes, int n_in,
                              void* d_out, int out_size, void* d_ws, size_t ws_size,
                              hipStream_t stream) {
    const float* u_in      = (const float*)d_in[0];
    const float* conv_w    = (const float*)d_in[1];
    const float* conv_b    = (const float*)d_in[2];
    const float* cat_table = (const float*)d_in[3];
    // d_in[4..6] (num_rows, cat_rows, num_types) are redundant with u_in[:,:,2]
    float* out = (float*)d_out;

    const int block = 256;
    const int grid  = 2048;   // 8 blocks/CU on 256 CUs; grid-stride covers the rest
    preset_embed_kernel<<<grid, block, 0, stream>>>(u_in, conv_w, conv_b, cat_table, out);
}